// Round 1
// baseline (508.613 us; speedup 1.0000x reference)
//
#include <hip/hip_runtime.h>
#include <hip/hip_bf16.h>

using f32x4 = __attribute__((ext_vector_type(4))) float;
using s16x8 = __attribute__((ext_vector_type(8))) short;

#define DEVFN static __device__ __forceinline__

static constexpr int NCOL = 256;     // output/channel width of every GEMM
static constexpr int MROWS = 8192;   // graph nodes
static constexpr int BM = 64;
static constexpr int BK = 64;
static constexpr int THREADS = 512;  // 8 waves
static constexpr int KSPLIT = 2;

DEVFN unsigned short f2bf(float f) {
  union { float f; unsigned u; } x; x.f = f;
  unsigned u = x.u;
  u += 0x7fffu + ((u >> 16) & 1u);   // round-to-nearest-even
  return (unsigned short)(u >> 16);
}

DEVFN void async16(void* lds, const void* g) {
  __builtin_amdgcn_global_load_lds((const __attribute__((address_space(1))) unsigned*)g,
                                   (__attribute__((address_space(3))) unsigned*)lds,
                                   16, 0, 0);
}

// C[M,256] = A[M,K] @ B[K,256];  A row-major (f32 or bf16), B in P8 layout:
// element (k,j) at flat offset ((k>>3)*256 + j)*8 + (k&7)   (bf16)
// Writes f32 partials: Cpart[kh][M][256], kh = K-split half.
template<bool AF32>
__global__ __launch_bounds__(THREADS)
void gemm_p8(const void* __restrict__ Aany, int Kfull,
             const unsigned short* __restrict__ Bp8,
             float* __restrict__ Cpart)
{
  constexpr int ABYTES = AF32 ? (BM * BK * 4) : (BM * BK * 2);
  __shared__ __align__(16) unsigned char Ab[2][ABYTES];
  __shared__ __align__(16) unsigned short Bb[2][(BK / 8) * NCOL * 8]; // 32KB

  const int klen = Kfull / KSPLIT;
  const int nt = klen / BK;
  const int tile = blockIdx.x >> 1;
  const int kh = blockIdx.x & 1;
  const int k0 = kh * klen;
  const int tid = threadIdx.x;
  const int lane = tid & 63;
  const int wm = (tid >> 6) >> 2;   // 0..1
  const int wn = (tid >> 6) & 3;    // 0..3

  const char* Abase = (const char*)Aany;
  const size_t arow_bytes = (size_t)Kfull * (AF32 ? 4 : 2);

  auto stageA = [&](int buf, int t) {
    if constexpr (AF32) {
#pragma unroll
      for (int o = 0; o < 2; ++o) {
        int slot = o * 8192 + tid * 16;            // linear LDS dest (bytes)
        int row = slot >> 8;                        // 256 B per row (64 f32)
        int c = (slot >> 4) & 15;                   // 16B chunk in row
        int cs = c ^ (row & 7);                     // pre-swizzled SOURCE chunk
        const char* src = Abase + (size_t)(tile * BM + row) * arow_bytes
                          + (size_t)(k0 + t * BK) * 4 + cs * 16;
        async16(&Ab[buf][slot], src);
      }
    } else {
      int slot = tid * 16;                          // 8KB total, 1 op
      int row = slot >> 7;                          // 128 B per row (64 bf16)
      int c = (slot >> 4) & 7;
      int cs = c ^ (row & 7);
      const char* src = Abase + (size_t)(tile * BM + row) * arow_bytes
                        + (size_t)(k0 + t * BK) * 2 + cs * 16;
      async16(&Ab[buf][slot], src);
    }
  };

  auto stageB = [&](int buf, int t) {
    // P8 tile for k-range [k0+t*64, +64) is a CONTIGUOUS 32KB block.
    const unsigned short* src = Bp8 + (size_t)(k0 + t * BK) * 256 + tid * 8;
#pragma unroll
    for (int o = 0; o < 4; ++o)
      async16(&Bb[buf][o * 4096 + tid * 8], src + o * 4096);
  };

  f32x4 acc[2][4] = {};

  stageA(0, 0); stageB(0, 0);
  __syncthreads();                                   // drains vmcnt before barrier

  int cur = 0;
  for (int t = 0; t < nt; ++t) {
    if (t + 1 < nt) { stageA(cur ^ 1, t + 1); stageB(cur ^ 1, t + 1); }
    const int lr = lane & 15, lg = lane >> 4;
#pragma unroll
    for (int s = 0; s < 2; ++s) {                    // two k=32 sub-steps
      s16x8 a[2], b[4];
#pragma unroll
      for (int fm = 0; fm < 2; ++fm) {
        int r = wm * 32 + fm * 16 + lr;
        if constexpr (AF32) {
          int cb = s * 8 + lg * 2;
          f32x4 v0 = *(const f32x4*)&Ab[cur][r * 256 + (((cb + 0) ^ (r & 7)) * 16)];
          f32x4 v1 = *(const f32x4*)&Ab[cur][r * 256 + (((cb + 1) ^ (r & 7)) * 16)];
          union { s16x8 v; unsigned short u[8]; } pk;
          pk.u[0] = f2bf(v0[0]); pk.u[1] = f2bf(v0[1]);
          pk.u[2] = f2bf(v0[2]); pk.u[3] = f2bf(v0[3]);
          pk.u[4] = f2bf(v1[0]); pk.u[5] = f2bf(v1[1]);
          pk.u[6] = f2bf(v1[2]); pk.u[7] = f2bf(v1[3]);
          a[fm] = pk.v;
        } else {
          int c = s * 4 + lg;
          a[fm] = *(const s16x8*)&Ab[cur][r * 128 + ((c ^ (r & 7)) * 16)];
        }
      }
      int kcl = s * 4 + lg;
#pragma unroll
      for (int fn = 0; fn < 4; ++fn) {
        int col = wn * 64 + fn * 16 + lr;
        b[fn] = *(const s16x8*)&Bb[cur][kcl * 2048 + col * 8];
      }
#pragma unroll
      for (int fm = 0; fm < 2; ++fm)
#pragma unroll
        for (int fn = 0; fn < 4; ++fn)
          acc[fm][fn] = __builtin_amdgcn_mfma_f32_16x16x32_bf16(a[fm], b[fn], acc[fm][fn], 0, 0, 0);
    }
    __syncthreads();
    cur ^= 1;
  }

  float* Cout = Cpart + (size_t)kh * MROWS * NCOL;
#pragma unroll
  for (int fm = 0; fm < 2; ++fm) {
    int r0 = tile * BM + wm * 32 + fm * 16 + (lane >> 4) * 4;
#pragma unroll
    for (int fn = 0; fn < 4; ++fn) {
      int col = wn * 64 + fn * 16 + (lane & 15);
#pragma unroll
      for (int r = 0; r < 4; ++r)
        Cout[(size_t)(r0 + r) * NCOL + col] = acc[fm][fn][r];
    }
  }
}

// ---- small epilogue / conversion kernels -------------------------------

// f32 [K][256] -> P8 bf16
__global__ void k_convert_p8(const float* __restrict__ W, int K,
                             unsigned short* __restrict__ outp) {
  int tid = blockIdx.x * blockDim.x + threadIdx.x;
  if (tid >= K * NCOL / 4) return;
  int j = tid & (NCOL - 1);
  int i0 = (tid >> 8) << 2;
  unsigned short u[4];
#pragma unroll
  for (int r = 0; r < 4; ++r) u[r] = f2bf(W[(size_t)(i0 + r) * NCOL + j]);
  size_t off = ((size_t)(i0 >> 3) * NCOL + j) * 8 + (i0 & 7);
  *(ushort4*)&outp[off] = make_ushort4(u[0], u[1], u[2], u[3]);
}

// sum 2 partials, optional per-row filter scale, write P8 bf16
__global__ void k_reduce_p8(const float* __restrict__ P, const float* __restrict__ filt,
                            unsigned short* __restrict__ outp) {
  int tid = blockIdx.x * blockDim.x + threadIdx.x;   // 524288 threads
  int j = tid & (NCOL - 1);
  int i0 = (tid >> 8) << 2;
  unsigned short u[4];
#pragma unroll
  for (int r = 0; r < 4; ++r) {
    size_t o = (size_t)(i0 + r) * NCOL + j;
    float v = P[o] + P[(size_t)MROWS * NCOL + o];
    if (filt) v *= filt[i0 + r];
    u[r] = f2bf(v);
  }
  size_t off = ((size_t)(i0 >> 3) * NCOL + j) * 8 + (i0 & 7);
  *(ushort4*)&outp[off] = make_ushort4(u[0], u[1], u[2], u[3]);
}

// sum 2 partials, relu, write row-major bf16 (A-operand for next GEMM)
__global__ void k_reduce_relu(const float* __restrict__ P, unsigned short* __restrict__ h1) {
  size_t o = (size_t)(blockIdx.x * blockDim.x + threadIdx.x) * 4;
  float4 a = *(const float4*)&P[o];
  float4 b = *(const float4*)&P[(size_t)MROWS * NCOL + o];
  unsigned short u0 = f2bf(fmaxf(a.x + b.x, 0.f));
  unsigned short u1 = f2bf(fmaxf(a.y + b.y, 0.f));
  unsigned short u2 = f2bf(fmaxf(a.z + b.z, 0.f));
  unsigned short u3 = f2bf(fmaxf(a.w + b.w, 0.f));
  *(ushort4*)&h1[o] = make_ushort4(u0, u1, u2, u3);
}

// sum 2 partials, write f32 (final output)
__global__ void k_reduce_f32(const float* __restrict__ P, float* __restrict__ out) {
  size_t o = (size_t)(blockIdx.x * blockDim.x + threadIdx.x) * 4;
  float4 a = *(const float4*)&P[o];
  float4 b = *(const float4*)&P[(size_t)MROWS * NCOL + o];
  float4 r; r.x = a.x + b.x; r.y = a.y + b.y; r.z = a.z + b.z; r.w = a.w + b.w;
  *(float4*)&out[o] = r;
}

extern "C" void kernel_launch(void* const* d_in, const int* in_sizes, int n_in,
                              void* d_out, int out_size, void* d_ws, size_t ws_size,
                              hipStream_t stream) {
  const float* input = (const float*)d_in[0];
  const float* Wv    = (const float*)d_in[1];
  const float* Winv  = (const float*)d_in[2];
  const float* W1    = (const float*)d_in[3];
  const float* W2    = (const float*)d_in[4];
  const float* f1    = (const float*)d_in[5];
  const float* f2    = (const float*)d_in[6];
  float* out = (float*)d_out;

  char* ws = (char*)d_ws;
  unsigned short* W1p = (unsigned short*)(ws);               // 256KB
  unsigned short* W2p = (unsigned short*)(ws + 0x40000);     // 128KB
  unsigned short* t1p = (unsigned short*)(ws + 0x60000);     // 4MB each
  unsigned short* s1p = (unsigned short*)(ws + 0x460000);
  unsigned short* t2p = (unsigned short*)(ws + 0x860000);
  unsigned short* s2p = (unsigned short*)(ws + 0xC60000);
  unsigned short* h1  = (unsigned short*)(ws + 0x1060000);
  float* part         = (float*)(ws + 0x1460000);            // 16MB

  dim3 gT(THREADS), gG((MROWS / BM) * KSPLIT);               // 256 WGs
  dim3 rT(256), rG(MROWS * NCOL / 4 / 256);                  // 2048 WGs

  k_convert_p8<<<dim3(128), rT, 0, stream>>>(W1, 512, W1p);
  k_convert_p8<<<dim3(64),  rT, 0, stream>>>(W2, 256, W2p);

  // t1 = input @ W1
  gemm_p8<true><<<gG, gT, 0, stream>>>((const void*)input, 512, W1p, part);
  k_reduce_p8<<<rG, rT, 0, stream>>>(part, (const float*)nullptr, t1p);
  // s1 = Winv @ t1, rows scaled by filter1
  gemm_p8<true><<<gG, gT, 0, stream>>>((const void*)Winv, 8192, t1p, part);
  k_reduce_p8<<<rG, rT, 0, stream>>>(part, f1, s1p);
  // h1 = relu(Wv @ s1), row-major bf16
  gemm_p8<true><<<gG, gT, 0, stream>>>((const void*)Wv, 8192, s1p, part);
  k_reduce_relu<<<rG, rT, 0, stream>>>(part, h1);
  // t2 = h1 @ W2
  gemm_p8<false><<<gG, gT, 0, stream>>>((const void*)h1, 256, W2p, part);
  k_reduce_p8<<<rG, rT, 0, stream>>>(part, (const float*)nullptr, t2p);
  // s2 = Winv @ t2, rows scaled by filter2
  gemm_p8<true><<<gG, gT, 0, stream>>>((const void*)Winv, 8192, t2p, part);
  k_reduce_p8<<<rG, rT, 0, stream>>>(part, f2, s2p);
  // out = Wv @ s2, f32
  gemm_p8<true><<<gG, gT, 0, stream>>>((const void*)Wv, 8192, s2p, part);
  k_reduce_f32<<<rG, rT, 0, stream>>>(part, out);
}

// Round 2
// 466.733 us; speedup vs baseline: 1.0897x; 1.0897x over previous
//
#include <hip/hip_runtime.h>
#include <hip/hip_bf16.h>

using f32x4 = __attribute__((ext_vector_type(4))) float;
using s16x8 = __attribute__((ext_vector_type(8))) short;

#define DEVFN static __device__ __forceinline__

static constexpr int NCOL = 256;     // output width of every GEMM
static constexpr int MROWS = 8192;   // rows of every GEMM
static constexpr int BM = 64;
static constexpr int BK = 64;
static constexpr int THREADS = 512;  // 8 waves
static constexpr int KSPLIT = 4;
static constexpr int NTILE = MROWS / BM;   // 128

DEVFN unsigned short f2bf(float f) {
  union { float f; unsigned u; } x; x.f = f;
  unsigned u = x.u;
  u += 0x7fffu + ((u >> 16) & 1u);   // round-to-nearest-even
  return (unsigned short)(u >> 16);
}

DEVFN void async16(void* lds, const void* g) {
  __builtin_amdgcn_global_load_lds((const __attribute__((address_space(1))) unsigned*)g,
                                   (__attribute__((address_space(3))) unsigned*)lds,
                                   16, 0, 0);
}

// C[M,256] = A[M,K] @ B[K,256]
//  A row-major. CVT=false: A bf16, staged via global_load_lds.
//  CVT=true: A f32, reg-staged + converted to bf16 once per element per block;
//            WB=true additionally writes the bf16 copy to Awb (each element is
//            staged exactly once across the tile x kh block grid).
//  B in P8 layout: element (k,j) at ((k>>3)*256 + j)*8 + (k&7), bf16.
//  Writes f32 partials Cpart[kh][M][256], kh = 0..KSPLIT-1.
template<bool CVT, bool WB>
__global__ __launch_bounds__(THREADS, 4)
void gemm_k(const void* __restrict__ Aany, int Kfull,
            const unsigned short* __restrict__ Bp8,
            float* __restrict__ Cpart,
            unsigned short* __restrict__ Awb)
{
  __shared__ __align__(16) unsigned short Ab[2][BM * BK];          // 2 x 8KB
  __shared__ __align__(16) unsigned short Bb[2][(BK / 8) * NCOL * 8]; // 2 x 32KB
  // total 80KB -> exactly 2 blocks/CU

  // XCD-chunked swizzle: blocks on XCD x get logical ids [x*q, (x+1)*q),
  // logical = kh*NTILE + tile so one XCD's chunk shares a single B k-panel.
  const int nwg = NTILE * KSPLIT;            // 512
  const int q = nwg / 8;
  const int logical = (blockIdx.x & 7) * q + (blockIdx.x >> 3);
  const int kh = logical / NTILE;
  const int tile = logical % NTILE;

  const int klen = Kfull / KSPLIT;
  const int nt = klen / BK;
  const int k0 = kh * klen;
  const int tid = threadIdx.x;
  const int lane = tid & 63;
  const int wm = (tid >> 6) >> 2;   // 0..1
  const int wn = (tid >> 6) & 3;    // 0..3

  const char* Abase = (const char*)Aany;

  // ---- staging helpers ----
  auto stageB = [&](int buf, int t) {
    const unsigned short* src = Bp8 + (size_t)(k0 + t * BK) * 256 + tid * 8;
#pragma unroll
    for (int o = 0; o < 4; ++o)
      async16(&Bb[buf][o * 4096 + tid * 8], src + o * 4096);
  };

  const int srow = tid >> 3;        // 0..63
  const int scj  = tid & 7;         // 8-elem chunk within the 64-k tile

  auto stageA_bf = [&](int buf, int t) {
    int cs = scj ^ (srow & 7);      // pre-swizzled SOURCE chunk, linear dest
    const char* src = Abase + (size_t)(tile * BM + srow) * (Kfull * 2)
                      + (size_t)(k0 + t * BK) * 2 + cs * 16;
    async16(&Ab[buf][tid * 8], src);
  };

  auto loadA_f32 = [&](int t, f32x4& v0, f32x4& v1) {
    const float* src = (const float*)Abase + (size_t)(tile * BM + srow) * Kfull
                       + k0 + t * BK + scj * 8;
    v0 = *(const f32x4*)src;
    v1 = *(const f32x4*)(src + 4);
  };

  auto writeA = [&](int buf, int t, const f32x4& v0, const f32x4& v1) {
    union { s16x8 v; unsigned short u[8]; } pk;
    pk.u[0] = f2bf(v0[0]); pk.u[1] = f2bf(v0[1]);
    pk.u[2] = f2bf(v0[2]); pk.u[3] = f2bf(v0[3]);
    pk.u[4] = f2bf(v1[0]); pk.u[5] = f2bf(v1[1]);
    pk.u[6] = f2bf(v1[2]); pk.u[7] = f2bf(v1[3]);
    *(s16x8*)&Ab[buf][srow * 64 + ((scj ^ (srow & 7)) * 8)] = pk.v;
    if constexpr (WB)
      *(s16x8*)&Awb[(size_t)(tile * BM + srow) * Kfull + k0 + t * BK + scj * 8] = pk.v;
  };

  f32x4 acc[2][4] = {};

  // ---- prologue: stage tile 0 ----
  if constexpr (CVT) {
    stageB(0, 0);
    f32x4 v0, v1; loadA_f32(0, v0, v1);
    writeA(0, 0, v0, v1);
  } else {
    stageA_bf(0, 0); stageB(0, 0);
  }
  __syncthreads();

  int cur = 0;
  const int lr = lane & 15, lg = lane >> 4;
  for (int t = 0; t < nt; ++t) {
    const bool pre = (t + 1 < nt);
    f32x4 n0, n1;
    if (pre) {
      stageB(cur ^ 1, t + 1);
      if constexpr (CVT) loadA_f32(t + 1, n0, n1);
      else stageA_bf(cur ^ 1, t + 1);
    }
#pragma unroll
    for (int s = 0; s < 2; ++s) {                    // two k=32 sub-steps
      s16x8 a[2], b[4];
      const int c = s * 4 + lg;
#pragma unroll
      for (int fm = 0; fm < 2; ++fm) {
        int r = wm * 32 + fm * 16 + lr;
        a[fm] = *(const s16x8*)&Ab[cur][r * 64 + ((c ^ (r & 7)) * 8)];
      }
#pragma unroll
      for (int fn = 0; fn < 4; ++fn) {
        int col = wn * 64 + fn * 16 + lr;
        b[fn] = *(const s16x8*)&Bb[cur][c * 2048 + col * 8];
      }
#pragma unroll
      for (int fm = 0; fm < 2; ++fm)
#pragma unroll
        for (int fn = 0; fn < 4; ++fn)
          acc[fm][fn] = __builtin_amdgcn_mfma_f32_16x16x32_bf16(a[fm], b[fn], acc[fm][fn], 0, 0, 0);
    }
    if (pre) {
      if constexpr (CVT) writeA(cur ^ 1, t + 1, n0, n1);
    }
    __syncthreads();
    cur ^= 1;
  }

  float* Cout = Cpart + (size_t)kh * MROWS * NCOL;
#pragma unroll
  for (int fm = 0; fm < 2; ++fm) {
    int r0 = tile * BM + wm * 32 + fm * 16 + (lane >> 4) * 4;
#pragma unroll
    for (int fn = 0; fn < 4; ++fn) {
      int col = wn * 64 + fn * 16 + (lane & 15);
#pragma unroll
      for (int r = 0; r < 4; ++r)
        Cout[(size_t)(r0 + r) * NCOL + col] = acc[fm][fn][r];
    }
  }
}

// ---- small epilogue / conversion kernels -------------------------------

// f32 [K][256] -> P8 bf16
__global__ void k_convert_p8(const float* __restrict__ W, int K,
                             unsigned short* __restrict__ outp) {
  int tid = blockIdx.x * blockDim.x + threadIdx.x;
  if (tid >= K * NCOL / 4) return;
  int j = tid & (NCOL - 1);
  int i0 = (tid >> 8) << 2;
  unsigned short u[4];
#pragma unroll
  for (int r = 0; r < 4; ++r) u[r] = f2bf(W[(size_t)(i0 + r) * NCOL + j]);
  size_t off = ((size_t)(i0 >> 3) * NCOL + j) * 8 + (i0 & 7);
  *(ushort4*)&outp[off] = make_ushort4(u[0], u[1], u[2], u[3]);
}

// sum KSPLIT partials, optional per-row filter scale, write P8 bf16
__global__ void k_reduce_p8(const float* __restrict__ P, const float* __restrict__ filt,
                            unsigned short* __restrict__ outp) {
  int tid = blockIdx.x * blockDim.x + threadIdx.x;
  int j = tid & (NCOL - 1);
  int i0 = (tid >> 8) << 2;
  unsigned short u[4];
#pragma unroll
  for (int r = 0; r < 4; ++r) {
    size_t o = (size_t)(i0 + r) * NCOL + j;
    float v = 0.f;
#pragma unroll
    for (int h = 0; h < KSPLIT; ++h) v += P[(size_t)h * MROWS * NCOL + o];
    if (filt) v *= filt[i0 + r];
    u[r] = f2bf(v);
  }
  size_t off = ((size_t)(i0 >> 3) * NCOL + j) * 8 + (i0 & 7);
  *(ushort4*)&outp[off] = make_ushort4(u[0], u[1], u[2], u[3]);
}

// sum partials, relu, write row-major bf16 (A-operand for next GEMM)
__global__ void k_reduce_relu(const float* __restrict__ P, unsigned short* __restrict__ h1) {
  size_t o = (size_t)(blockIdx.x * blockDim.x + threadIdx.x) * 4;
  float4 v = *(const float4*)&P[o];
#pragma unroll
  for (int h = 1; h < KSPLIT; ++h) {
    float4 b = *(const float4*)&P[(size_t)h * MROWS * NCOL + o];
    v.x += b.x; v.y += b.y; v.z += b.z; v.w += b.w;
  }
  unsigned short u0 = f2bf(fmaxf(v.x, 0.f));
  unsigned short u1 = f2bf(fmaxf(v.y, 0.f));
  unsigned short u2 = f2bf(fmaxf(v.z, 0.f));
  unsigned short u3 = f2bf(fmaxf(v.w, 0.f));
  *(ushort4*)&h1[o] = make_ushort4(u0, u1, u2, u3);
}

// sum partials, write f32 (final output)
__global__ void k_reduce_f32(const float* __restrict__ P, float* __restrict__ out) {
  size_t o = (size_t)(blockIdx.x * blockDim.x + threadIdx.x) * 4;
  float4 v = *(const float4*)&P[o];
#pragma unroll
  for (int h = 1; h < KSPLIT; ++h) {
    float4 b = *(const float4*)&P[(size_t)h * MROWS * NCOL + o];
    v.x += b.x; v.y += b.y; v.z += b.z; v.w += b.w;
  }
  *(float4*)&out[o] = v;
}

extern "C" void kernel_launch(void* const* d_in, const int* in_sizes, int n_in,
                              void* d_out, int out_size, void* d_ws, size_t ws_size,
                              hipStream_t stream) {
  const float* input = (const float*)d_in[0];
  const float* Wv    = (const float*)d_in[1];
  const float* Winv  = (const float*)d_in[2];
  const float* W1    = (const float*)d_in[3];
  const float* W2    = (const float*)d_in[4];
  const float* f1    = (const float*)d_in[5];
  const float* f2    = (const float*)d_in[6];
  float* out = (float*)d_out;

  char* ws = (char*)d_ws;
  unsigned short* WvBf   = (unsigned short*)(ws);                 // 128MB
  unsigned short* WinvBf = (unsigned short*)(ws + 0x8000000);     // 128MB
  float* part            = (float*)(ws + 0x10000000);             // 32MB
  unsigned short* W1p    = (unsigned short*)(ws + 0x12000000);    // 256KB
  unsigned short* W2p    = (unsigned short*)(ws + 0x12040000);    // 128KB
  unsigned short* t1p    = (unsigned short*)(ws + 0x12060000);    // 4MB each
  unsigned short* s1p    = (unsigned short*)(ws + 0x12460000);
  unsigned short* t2p    = (unsigned short*)(ws + 0x12860000);
  unsigned short* s2p    = (unsigned short*)(ws + 0x12C60000);
  unsigned short* h1     = (unsigned short*)(ws + 0x13060000);

  dim3 gT(THREADS), gG(NTILE * KSPLIT);                // 512 WGs, 2/CU
  dim3 rT(256), rG(MROWS * NCOL / 4 / 256);            // 2048 WGs

  k_convert_p8<<<dim3(128), rT, 0, stream>>>(W1, 512, W1p);
  k_convert_p8<<<dim3(64),  rT, 0, stream>>>(W2, 256, W2p);

  // t1 = input @ W1                     (A f32, convert in-kernel, no writeback)
  gemm_k<true, false><<<gG, gT, 0, stream>>>((const void*)input, 512, W1p, part, nullptr);
  k_reduce_p8<<<rG, rT, 0, stream>>>(part, (const float*)nullptr, t1p);
  // s1 = diag(f1) . (Winv @ t1)         (A f32 -> also emit Winv bf16 copy)
  gemm_k<true, true><<<gG, gT, 0, stream>>>((const void*)Winv, 8192, t1p, part, WinvBf);
  k_reduce_p8<<<rG, rT, 0, stream>>>(part, f1, s1p);
  // h1 = relu(Wv @ s1)                  (A f32 -> also emit Wv bf16 copy)
  gemm_k<true, true><<<gG, gT, 0, stream>>>((const void*)Wv, 8192, s1p, part, WvBf);
  k_reduce_relu<<<rG, rT, 0, stream>>>(part, h1);
  // t2 = h1 @ W2                        (A bf16 row-major)
  gemm_k<false, false><<<gG, gT, 0, stream>>>((const void*)h1, 256, W2p, part, nullptr);
  k_reduce_p8<<<rG, rT, 0, stream>>>(part, (const float*)nullptr, t2p);
  // s2 = diag(f2) . (Winv @ t2)         (A bf16 copy)
  gemm_k<false, false><<<gG, gT, 0, stream>>>((const void*)WinvBf, 8192, t2p, part, nullptr);
  k_reduce_p8<<<rG, rT, 0, stream>>>(part, f2, s2p);
  // out = Wv @ s2                       (A bf16 copy, f32 output)
  gemm_k<false, false><<<gG, gT, 0, stream>>>((const void*)WvBf, 8192, s2p, part, nullptr);
  k_reduce_f32<<<rG, rT, 0, stream>>>(part, out);
}